// Round 8
// baseline (354.630 us; speedup 1.0000x reference)
//
#include <hip/hip_runtime.h>
#include <math.h>

// LSTMNextWindowPredictor via fp16 single-product MFMA: B=262144, I=13, H=64,
// T=5, O=13, fp32 in/out. Per wave: M=32 rows. Per t:
//   G[32x256] = X_t[32x13(pad32)] @ W_ih^T + H[32x64] @ W_hh^T
// via mfma_f32_16x16x32_f16 (fp32 accumulate), then elementwise LSTM update.
// h lives per-wave in LDS as fp16 in A-fragment k-contiguous layout (XOR
// swizzled by row&7) -> A-frag loads are pure ds_read_b128.
// R8 = R4 (proven 195 us; W_hh staged in LDS) with 512-thread blocks: the
// 32 KB whh_lds is shared by 8 waves instead of 4 -> 64 KB/block, 2 blocks/CU
// = 16 waves/CU (50% occ) vs R4's 12 (30%). launch_bounds(512,2) = 256-reg
// budget, far above the ~72-reg live set (R5/R6 lesson: tight caps spill).
// x loads nontemporal: the once-read 68 MB stream must not evict L1/L2-hot
// W_ih/W1/W2 frags (R7 lesson: weight-frag L2 thrash costs 125 MB of HBM).

#define TT 5
#define NI 13

typedef _Float16 half8 __attribute__((ext_vector_type(8)));
typedef __attribute__((ext_vector_type(4))) float f32x4;

// ws byte offsets
#define WHH_OFF  0       // 16384 halves [kt2][nt16][lane64][j8]  (32 KB)
#define WIH_OFF  32768   // 4096 halves  [nt16][l32][j8] (quads 2,3 alias; A-side zeros cover)
#define W1_OFF   40960   // 4096 halves  [kt2][nt4][lane64][j8]
#define W2_OFF   49152   // 1024 halves  [kt2][lane64][j8] (n>=13 zero)
#define BIAS_OFF 51200   // 256 floats (b_ih + b_hh), layout [g*4+jt][mcol]

#define LOG2E 1.44269504088896340736f

__device__ __forceinline__ float fexp(float v) {  // e^v via v_exp_f32 (2^x)
  return __builtin_amdgcn_exp2f(v * LOG2E);
}
__device__ __forceinline__ float fsig(float v) {  // 1/(1+e^-v), v_rcp_f32
  return __builtin_amdgcn_rcpf(1.f + fexp(-v));
}
__device__ __forceinline__ float ftanh(float v) { // 1 - 2/(1+e^{2v})
  return fmaf(-2.f, __builtin_amdgcn_rcpf(1.f + fexp(2.f * v)), 1.f);
}

__global__ void prep_kernel(const float* __restrict__ W_ih,
                            const float* __restrict__ W_hh,
                            const float* __restrict__ b_ih,
                            const float* __restrict__ b_hh,
                            const float* __restrict__ W1,
                            const float* __restrict__ W2,
                            _Float16* __restrict__ whh,
                            _Float16* __restrict__ wih,
                            _Float16* __restrict__ w1,
                            _Float16* __restrict__ w2,
                            float* __restrict__ bias) {
  int idx = blockIdx.x * 256 + threadIdx.x;
  if (idx < 16384) {  // W_hh B-frags: B[k][n] = W_hh[n*64+k]
    int kt = idx >> 13, r = idx & 8191;
    int nt = r >> 9, lane = (r >> 3) & 63, j = idx & 7;
    int k = kt * 32 + ((lane >> 4) << 3) + j;
    int n = (nt << 4) + (lane & 15);
    whh[idx] = (_Float16)W_hh[n * 64 + k];
  }
  if (idx < 4096) {   // W_ih B-frags, k tile of 32 (k>=13 zero)
    int nt = idx >> 8, l32 = (idx >> 3) & 31, j = idx & 7;
    int k = ((l32 >> 4) << 3) + j;
    int n = (nt << 4) + (l32 & 15);
    wih[idx] = (_Float16)((k < NI) ? W_ih[n * NI + k] : 0.f);
  }
  if (idx < 4096) {   // W1 B-frags: B[k][n] = W1[n*64+k]
    int kt = idx >> 11, r = idx & 2047;
    int nt = r >> 9, lane = (r >> 3) & 63, j = idx & 7;
    int k = kt * 32 + ((lane >> 4) << 3) + j;
    int n = (nt << 4) + (lane & 15);
    w1[idx] = (_Float16)W1[n * 64 + k];
  }
  if (idx < 1024) {   // W2 B-frags (n>=13 zero)
    int kt = idx >> 9, lane = (idx >> 3) & 63, j = idx & 7;
    int k = kt * 32 + ((lane >> 4) << 3) + j;
    int n = lane & 15;
    w2[idx] = (_Float16)((n < 13) ? W2[n * 64 + k] : 0.f);
  }
  if (idx < 256) bias[idx] = b_ih[idx] + b_hh[idx];
}

// Read A-fragments (rows mt*16+mcol, k = kt*32+quad*8+j) from swizzled fp16 LDS.
__device__ __forceinline__ void read_afrags(const _Float16* __restrict__ hw,
                                            int quad, int mcol, half8 a[2][2]) {
#pragma unroll
  for (int mt = 0; mt < 2; ++mt) {
    const int r = mt * 16 + mcol;
#pragma unroll
    for (int kt = 0; kt < 2; ++kt) {
      const int blk = (kt * 4 + quad) ^ (r & 7);
      a[mt][kt] = *(const half8*)&hw[r * 64 + blk * 8];
    }
  }
}

__global__ __launch_bounds__(512, 2)
void lstm_mfma(const float* __restrict__ x,
               const _Float16* __restrict__ whh_g,
               const _Float16* __restrict__ wih_g,
               const _Float16* __restrict__ w1_g,
               const _Float16* __restrict__ w2_g,
               const float* __restrict__ biasp,
               const float* __restrict__ b1v,
               const float* __restrict__ b2v,
               float* __restrict__ out) {
  __shared__ __attribute__((aligned(16))) _Float16 whh_lds[16384];  // 32 KB
  __shared__ __attribute__((aligned(16))) _Float16 hshm[8][2048];   // 32 KB

  const int tid = threadIdx.x;
  const int wave = tid >> 6;
  const int lane = tid & 63;
  const int quad = lane >> 4;
  const int mcol = lane & 15;
  _Float16* __restrict__ hw = &hshm[wave][0];
  const int row0 = blockIdx.x * 256 + wave * 32;

  // stage W_hh fragments into LDS (one-time, coalesced 16B, 512 threads)
  {
    const f32x4* __restrict__ s = (const f32x4*)whh_g;
    f32x4* d = (f32x4*)whh_lds;
#pragma unroll
    for (int i = 0; i < 4; ++i) d[tid + 512 * i] = s[tid + 512 * i];
  }
  __syncthreads();

  float c_st[2][4][4];
#pragma unroll
  for (int mt = 0; mt < 2; ++mt)
#pragma unroll
    for (int jt = 0; jt < 4; ++jt)
#pragma unroll
      for (int r = 0; r < 4; ++r) c_st[mt][jt][r] = 0.f;

  float bias_r[4][4];  // [g][jt]: per-lane col = (g*4+jt)*16 + mcol
#pragma unroll
  for (int g = 0; g < 4; ++g)
#pragma unroll
    for (int jt = 0; jt < 4; ++jt)
      bias_r[g][jt] = biasp[((g * 4 + jt) << 4) + mcol];

  const half8* __restrict__ wihf = (const half8*)wih_g;
  const half8* __restrict__ whhf = (const half8*)whh_lds;

  // hoisted x row pointers
  const float* __restrict__ xp0 = x + (size_t)(row0 + mcol) * (TT * NI);
  const float* __restrict__ xp1 = x + (size_t)(row0 + 16 + mcol) * (TT * NI);

#pragma unroll 1
  for (int t = 0; t < TT; ++t) {
    // x A-fragments (k = quad*8+j, zero beyond 12); nontemporal: x is
    // read-once and must not evict weight frags from L1/L2.
    half8 xa[2];
#pragma unroll
    for (int mt = 0; mt < 2; ++mt) {
      const float* __restrict__ xp = (mt ? xp1 : xp0) + t * NI;
#pragma unroll
      for (int j = 0; j < 8; ++j) {
        const int k = quad * 8 + j;
        xa[mt][j] = (_Float16)((k < NI) ? __builtin_nontemporal_load(xp + k) : 0.f);
      }
    }

    half8 ah[2][2];
    if (t > 0) read_afrags(hw, quad, mcol, ah);

#pragma unroll 1
    for (int jt = 0; jt < 4; ++jt) {
      f32x4 acc[2][4];
#pragma unroll
      for (int mt = 0; mt < 2; ++mt)
#pragma unroll
        for (int g = 0; g < 4; ++g) {
          const float b = bias_r[g][jt];
          f32x4 z = {b, b, b, b};
          acc[mt][g] = z;
        }

      // x @ W_ih^T
#pragma unroll
      for (int g = 0; g < 4; ++g) {
        const half8 bfr = wihf[(g * 4 + jt) * 32 + (lane & 31)];
#pragma unroll
        for (int mt = 0; mt < 2; ++mt)
          acc[mt][g] = __builtin_amdgcn_mfma_f32_16x16x32_f16(xa[mt], bfr, acc[mt][g], 0, 0, 0);
      }

      // h @ W_hh^T (h==0 at t=0); B-frags from LDS (shared by 8 waves)
      if (t > 0) {
#pragma unroll
        for (int kt = 0; kt < 2; ++kt)
#pragma unroll
          for (int g = 0; g < 4; ++g) {
            const half8 bfr = whhf[(kt * 16 + g * 4 + jt) * 64 + lane];
#pragma unroll
            for (int mt = 0; mt < 2; ++mt)
              acc[mt][g] = __builtin_amdgcn_mfma_f32_16x16x32_f16(ah[mt][kt], bfr, acc[mt][g], 0, 0, 0);
          }
      }

      // elementwise LSTM update; lane owns rows quad*4+reg, col jt*16+mcol
#pragma unroll
      for (int mt = 0; mt < 2; ++mt)
#pragma unroll
        for (int reg = 0; reg < 4; ++reg) {
          const float gi = acc[mt][0][reg];
          const float gf = acc[mt][1][reg];
          const float gg = acc[mt][2][reg];
          const float go = acc[mt][3][reg];
          float cv = c_st[mt][jt][reg];
          cv = fsig(gf) * cv + fsig(gi) * ftanh(gg);
          c_st[mt][jt][reg] = cv;
          const float hn = fsig(go) * ftanh(cv);
          const int r = mt * 16 + quad * 4 + reg;
          const int k = jt * 16 + mcol;
          hw[r * 64 + (((k >> 3) ^ (r & 7)) << 3) + (k & 7)] = (_Float16)hn;
        }
    }
  }

  // ---- head: z = relu(h @ W1^T + b1), fp16 round-trip through LDS ----
  {
    half8 ah[2][2];
    read_afrags(hw, quad, mcol, ah);

    f32x4 zacc[2][4];
#pragma unroll
    for (int nt = 0; nt < 4; ++nt) {
      const float b = b1v[nt * 16 + mcol];
#pragma unroll
      for (int mt = 0; mt < 2; ++mt) {
        f32x4 z = {b, b, b, b};
        zacc[mt][nt] = z;
      }
    }
#pragma unroll
    for (int kt = 0; kt < 2; ++kt)
#pragma unroll
      for (int nt = 0; nt < 4; ++nt) {
        const half8 bfr = ((const half8*)w1_g)[(kt * 4 + nt) * 64 + lane];
#pragma unroll
        for (int mt = 0; mt < 2; ++mt)
          zacc[mt][nt] = __builtin_amdgcn_mfma_f32_16x16x32_f16(ah[mt][kt], bfr, zacc[mt][nt], 0, 0, 0);
      }
#pragma unroll
    for (int mt = 0; mt < 2; ++mt)
#pragma unroll
      for (int nt = 0; nt < 4; ++nt)
#pragma unroll
        for (int reg = 0; reg < 4; ++reg) {
          const float zv = fmaxf(zacc[mt][nt][reg], 0.f);
          const int r = mt * 16 + quad * 4 + reg;
          const int k = nt * 16 + mcol;
          hw[r * 64 + (((k >> 3) ^ (r & 7)) << 3) + (k & 7)] = (_Float16)zv;
        }
  }

  // ---- head: out = z @ W2^T + b2 ----
  {
    half8 zh[2][2];
    read_afrags(hw, quad, mcol, zh);

    const float b2r = (mcol < 13) ? b2v[mcol] : 0.f;
    f32x4 oacc[2];
#pragma unroll
    for (int mt = 0; mt < 2; ++mt) {
      f32x4 z = {b2r, b2r, b2r, b2r};
      oacc[mt] = z;
    }
#pragma unroll
    for (int kt = 0; kt < 2; ++kt) {
      const half8 bfr = ((const half8*)w2_g)[kt * 64 + lane];
#pragma unroll
      for (int mt = 0; mt < 2; ++mt)
        oacc[mt] = __builtin_amdgcn_mfma_f32_16x16x32_f16(zh[mt][kt], bfr, oacc[mt], 0, 0, 0);
    }
    if (mcol < 13) {
#pragma unroll
      for (int mt = 0; mt < 2; ++mt)
#pragma unroll
        for (int reg = 0; reg < 4; ++reg) {
          const int row = row0 + mt * 16 + quad * 4 + reg;
          out[row * 13 + mcol] = oacc[mt][reg];
        }
    }
  }
}

extern "C" void kernel_launch(void* const* d_in, const int* in_sizes, int n_in,
                              void* d_out, int out_size, void* d_ws, size_t ws_size,
                              hipStream_t stream) {
  const float* x    = (const float*)d_in[0];
  const float* W_ih = (const float*)d_in[1];
  const float* W_hh = (const float*)d_in[2];
  const float* b_ih = (const float*)d_in[3];
  const float* b_hh = (const float*)d_in[4];
  const float* W1   = (const float*)d_in[5];
  const float* b1   = (const float*)d_in[6];
  const float* W2   = (const float*)d_in[7];
  const float* b2   = (const float*)d_in[8];
  float* out = (float*)d_out;
  char* ws = (char*)d_ws;

  _Float16* whh = (_Float16*)(ws + WHH_OFF);
  _Float16* wih = (_Float16*)(ws + WIH_OFF);
  _Float16* w1  = (_Float16*)(ws + W1_OFF);
  _Float16* w2  = (_Float16*)(ws + W2_OFF);
  float* bias   = (float*)(ws + BIAS_OFF);

  hipLaunchKernelGGL(prep_kernel, dim3(64), dim3(256), 0, stream,
                     W_ih, W_hh, b_ih, b_hh, W1, W2, whh, wih, w1, w2, bias);

  const int B = in_sizes[0] / (TT * NI);  // 262144
  hipLaunchKernelGGL(lstm_mfma, dim3(B / 256), dim3(512), 0, stream,
                     x, whh, wih, w1, w2, bias, b1, b2, out);
}

// Round 9
// 274.977 us; speedup vs baseline: 1.2897x; 1.2897x over previous
//
#include <hip/hip_runtime.h>
#include <math.h>

// LSTMNextWindowPredictor via fp16 single-product MFMA: B=262144, I=13, H=64,
// T=5, O=13, fp32 in/out. Per wave: M=32 rows. Per t:
//   G[32x256] = X_t[32x13(pad32)] @ W_ih^T + H[32x64] @ W_hh^T
// via mfma_f32_16x16x32_f16 (fp32 accumulate), then elementwise LSTM update.
// h lives per-wave in LDS as fp16 in A-fragment k-contiguous layout (XOR
// swizzled by row&7) -> A-frag loads are pure ds_read_b128.
// R9 = R8 minus the nontemporal x loads (R8 lesson: NT bypassed L1 and
// re-fetched each 260 B x row 5x -> FETCH +47 MB, full-HBM-latency stalls,
// VALUBusy 57->41). x rows have real cross-t L1 reuse; weights are in LDS so
// there is nothing for NT to protect. Keep 512-thr blocks: 32 KB whh shared
// by 8 waves + 8x4 KB h = 64 KB -> 2 blocks/CU = 16 waves/CU, and keep the
// loose launch_bounds(512,2) (=256-reg budget): R8 was the first spill-free
// variant (WRITE exactly 13.3 MB, VGPR 80 natural).

#define TT 5
#define NI 13

typedef _Float16 half8 __attribute__((ext_vector_type(8)));
typedef __attribute__((ext_vector_type(4))) float f32x4;

// ws byte offsets
#define WHH_OFF  0       // 16384 halves [kt2][nt16][lane64][j8]  (32 KB)
#define WIH_OFF  32768   // 4096 halves  [nt16][l32][j8] (quads 2,3 alias; A-side zeros cover)
#define W1_OFF   40960   // 4096 halves  [kt2][nt4][lane64][j8]
#define W2_OFF   49152   // 1024 halves  [kt2][lane64][j8] (n>=13 zero)
#define BIAS_OFF 51200   // 256 floats (b_ih + b_hh), layout [g*4+jt][mcol]

#define LOG2E 1.44269504088896340736f

__device__ __forceinline__ float fexp(float v) {  // e^v via v_exp_f32 (2^x)
  return __builtin_amdgcn_exp2f(v * LOG2E);
}
__device__ __forceinline__ float fsig(float v) {  // 1/(1+e^-v), v_rcp_f32
  return __builtin_amdgcn_rcpf(1.f + fexp(-v));
}
__device__ __forceinline__ float ftanh(float v) { // 1 - 2/(1+e^{2v})
  return fmaf(-2.f, __builtin_amdgcn_rcpf(1.f + fexp(2.f * v)), 1.f);
}

__global__ void prep_kernel(const float* __restrict__ W_ih,
                            const float* __restrict__ W_hh,
                            const float* __restrict__ b_ih,
                            const float* __restrict__ b_hh,
                            const float* __restrict__ W1,
                            const float* __restrict__ W2,
                            _Float16* __restrict__ whh,
                            _Float16* __restrict__ wih,
                            _Float16* __restrict__ w1,
                            _Float16* __restrict__ w2,
                            float* __restrict__ bias) {
  int idx = blockIdx.x * 256 + threadIdx.x;
  if (idx < 16384) {  // W_hh B-frags: B[k][n] = W_hh[n*64+k]
    int kt = idx >> 13, r = idx & 8191;
    int nt = r >> 9, lane = (r >> 3) & 63, j = idx & 7;
    int k = kt * 32 + ((lane >> 4) << 3) + j;
    int n = (nt << 4) + (lane & 15);
    whh[idx] = (_Float16)W_hh[n * 64 + k];
  }
  if (idx < 4096) {   // W_ih B-frags, k tile of 32 (k>=13 zero)
    int nt = idx >> 8, l32 = (idx >> 3) & 31, j = idx & 7;
    int k = ((l32 >> 4) << 3) + j;
    int n = (nt << 4) + (l32 & 15);
    wih[idx] = (_Float16)((k < NI) ? W_ih[n * NI + k] : 0.f);
  }
  if (idx < 4096) {   // W1 B-frags: B[k][n] = W1[n*64+k]
    int kt = idx >> 11, r = idx & 2047;
    int nt = r >> 9, lane = (r >> 3) & 63, j = idx & 7;
    int k = kt * 32 + ((lane >> 4) << 3) + j;
    int n = (nt << 4) + (lane & 15);
    w1[idx] = (_Float16)W1[n * 64 + k];
  }
  if (idx < 1024) {   // W2 B-frags (n>=13 zero)
    int kt = idx >> 9, lane = (idx >> 3) & 63, j = idx & 7;
    int k = kt * 32 + ((lane >> 4) << 3) + j;
    int n = lane & 15;
    w2[idx] = (_Float16)((n < 13) ? W2[n * 64 + k] : 0.f);
  }
  if (idx < 256) bias[idx] = b_ih[idx] + b_hh[idx];
}

// Read A-fragments (rows mt*16+mcol, k = kt*32+quad*8+j) from swizzled fp16 LDS.
__device__ __forceinline__ void read_afrags(const _Float16* __restrict__ hw,
                                            int quad, int mcol, half8 a[2][2]) {
#pragma unroll
  for (int mt = 0; mt < 2; ++mt) {
    const int r = mt * 16 + mcol;
#pragma unroll
    for (int kt = 0; kt < 2; ++kt) {
      const int blk = (kt * 4 + quad) ^ (r & 7);
      a[mt][kt] = *(const half8*)&hw[r * 64 + blk * 8];
    }
  }
}

__global__ __launch_bounds__(512, 2)
void lstm_mfma(const float* __restrict__ x,
               const _Float16* __restrict__ whh_g,
               const _Float16* __restrict__ wih_g,
               const _Float16* __restrict__ w1_g,
               const _Float16* __restrict__ w2_g,
               const float* __restrict__ biasp,
               const float* __restrict__ b1v,
               const float* __restrict__ b2v,
               float* __restrict__ out) {
  __shared__ __attribute__((aligned(16))) _Float16 whh_lds[16384];  // 32 KB
  __shared__ __attribute__((aligned(16))) _Float16 hshm[8][2048];   // 32 KB

  const int tid = threadIdx.x;
  const int wave = tid >> 6;
  const int lane = tid & 63;
  const int quad = lane >> 4;
  const int mcol = lane & 15;
  _Float16* __restrict__ hw = &hshm[wave][0];
  const int row0 = blockIdx.x * 256 + wave * 32;

  // stage W_hh fragments into LDS (one-time, coalesced 16B, 512 threads)
  {
    const f32x4* __restrict__ s = (const f32x4*)whh_g;
    f32x4* d = (f32x4*)whh_lds;
#pragma unroll
    for (int i = 0; i < 4; ++i) d[tid + 512 * i] = s[tid + 512 * i];
  }
  __syncthreads();

  float c_st[2][4][4];
#pragma unroll
  for (int mt = 0; mt < 2; ++mt)
#pragma unroll
    for (int jt = 0; jt < 4; ++jt)
#pragma unroll
      for (int r = 0; r < 4; ++r) c_st[mt][jt][r] = 0.f;

  float bias_r[4][4];  // [g][jt]: per-lane col = (g*4+jt)*16 + mcol
#pragma unroll
  for (int g = 0; g < 4; ++g)
#pragma unroll
    for (int jt = 0; jt < 4; ++jt)
      bias_r[g][jt] = biasp[((g * 4 + jt) << 4) + mcol];

  const half8* __restrict__ wihf = (const half8*)wih_g;
  const half8* __restrict__ whhf = (const half8*)whh_lds;

  // hoisted x row pointers
  const float* __restrict__ xp0 = x + (size_t)(row0 + mcol) * (TT * NI);
  const float* __restrict__ xp1 = x + (size_t)(row0 + 16 + mcol) * (TT * NI);

#pragma unroll 1
  for (int t = 0; t < TT; ++t) {
    // x A-fragments (k = quad*8+j, zero beyond 12); plain loads: rows have
    // cross-t L1 reuse (260 B row read over 5 timesteps).
    half8 xa[2];
#pragma unroll
    for (int mt = 0; mt < 2; ++mt) {
      const float* __restrict__ xp = (mt ? xp1 : xp0) + t * NI;
#pragma unroll
      for (int j = 0; j < 8; ++j) {
        const int k = quad * 8 + j;
        xa[mt][j] = (_Float16)((k < NI) ? xp[k] : 0.f);
      }
    }

    half8 ah[2][2];
    if (t > 0) read_afrags(hw, quad, mcol, ah);

#pragma unroll 1
    for (int jt = 0; jt < 4; ++jt) {
      f32x4 acc[2][4];
#pragma unroll
      for (int mt = 0; mt < 2; ++mt)
#pragma unroll
        for (int g = 0; g < 4; ++g) {
          const float b = bias_r[g][jt];
          f32x4 z = {b, b, b, b};
          acc[mt][g] = z;
        }

      // x @ W_ih^T
#pragma unroll
      for (int g = 0; g < 4; ++g) {
        const half8 bfr = wihf[(g * 4 + jt) * 32 + (lane & 31)];
#pragma unroll
        for (int mt = 0; mt < 2; ++mt)
          acc[mt][g] = __builtin_amdgcn_mfma_f32_16x16x32_f16(xa[mt], bfr, acc[mt][g], 0, 0, 0);
      }

      // h @ W_hh^T (h==0 at t=0); B-frags from LDS (shared by 8 waves)
      if (t > 0) {
#pragma unroll
        for (int kt = 0; kt < 2; ++kt)
#pragma unroll
          for (int g = 0; g < 4; ++g) {
            const half8 bfr = whhf[(kt * 16 + g * 4 + jt) * 64 + lane];
#pragma unroll
            for (int mt = 0; mt < 2; ++mt)
              acc[mt][g] = __builtin_amdgcn_mfma_f32_16x16x32_f16(ah[mt][kt], bfr, acc[mt][g], 0, 0, 0);
          }
      }

      // elementwise LSTM update; lane owns rows quad*4+reg, col jt*16+mcol
#pragma unroll
      for (int mt = 0; mt < 2; ++mt)
#pragma unroll
        for (int reg = 0; reg < 4; ++reg) {
          const float gi = acc[mt][0][reg];
          const float gf = acc[mt][1][reg];
          const float gg = acc[mt][2][reg];
          const float go = acc[mt][3][reg];
          float cv = c_st[mt][jt][reg];
          cv = fsig(gf) * cv + fsig(gi) * ftanh(gg);
          c_st[mt][jt][reg] = cv;
          const float hn = fsig(go) * ftanh(cv);
          const int r = mt * 16 + quad * 4 + reg;
          const int k = jt * 16 + mcol;
          hw[r * 64 + (((k >> 3) ^ (r & 7)) << 3) + (k & 7)] = (_Float16)hn;
        }
    }
  }

  // ---- head: z = relu(h @ W1^T + b1), fp16 round-trip through LDS ----
  {
    half8 ah[2][2];
    read_afrags(hw, quad, mcol, ah);

    f32x4 zacc[2][4];
#pragma unroll
    for (int nt = 0; nt < 4; ++nt) {
      const float b = b1v[nt * 16 + mcol];
#pragma unroll
      for (int mt = 0; mt < 2; ++mt) {
        f32x4 z = {b, b, b, b};
        zacc[mt][nt] = z;
      }
    }
#pragma unroll
    for (int kt = 0; kt < 2; ++kt)
#pragma unroll
      for (int nt = 0; nt < 4; ++nt) {
        const half8 bfr = ((const half8*)w1_g)[(kt * 4 + nt) * 64 + lane];
#pragma unroll
        for (int mt = 0; mt < 2; ++mt)
          zacc[mt][nt] = __builtin_amdgcn_mfma_f32_16x16x32_f16(ah[mt][kt], bfr, zacc[mt][nt], 0, 0, 0);
      }
#pragma unroll
    for (int mt = 0; mt < 2; ++mt)
#pragma unroll
      for (int nt = 0; nt < 4; ++nt)
#pragma unroll
        for (int reg = 0; reg < 4; ++reg) {
          const float zv = fmaxf(zacc[mt][nt][reg], 0.f);
          const int r = mt * 16 + quad * 4 + reg;
          const int k = nt * 16 + mcol;
          hw[r * 64 + (((k >> 3) ^ (r & 7)) << 3) + (k & 7)] = (_Float16)zv;
        }
  }

  // ---- head: out = z @ W2^T + b2 ----
  {
    half8 zh[2][2];
    read_afrags(hw, quad, mcol, zh);

    const float b2r = (mcol < 13) ? b2v[mcol] : 0.f;
    f32x4 oacc[2];
#pragma unroll
    for (int mt = 0; mt < 2; ++mt) {
      f32x4 z = {b2r, b2r, b2r, b2r};
      oacc[mt] = z;
    }
#pragma unroll
    for (int kt = 0; kt < 2; ++kt) {
      const half8 bfr = ((const half8*)w2_g)[kt * 64 + lane];
#pragma unroll
      for (int mt = 0; mt < 2; ++mt)
        oacc[mt] = __builtin_amdgcn_mfma_f32_16x16x32_f16(zh[mt][kt], bfr, oacc[mt], 0, 0, 0);
    }
    if (mcol < 13) {
#pragma unroll
      for (int mt = 0; mt < 2; ++mt)
#pragma unroll
        for (int reg = 0; reg < 4; ++reg) {
          const int row = row0 + mt * 16 + quad * 4 + reg;
          out[row * 13 + mcol] = oacc[mt][reg];
        }
    }
  }
}

extern "C" void kernel_launch(void* const* d_in, const int* in_sizes, int n_in,
                              void* d_out, int out_size, void* d_ws, size_t ws_size,
                              hipStream_t stream) {
  const float* x    = (const float*)d_in[0];
  const float* W_ih = (const float*)d_in[1];
  const float* W_hh = (const float*)d_in[2];
  const float* b_ih = (const float*)d_in[3];
  const float* b_hh = (const float*)d_in[4];
  const float* W1   = (const float*)d_in[5];
  const float* b1   = (const float*)d_in[6];
  const float* W2   = (const float*)d_in[7];
  const float* b2   = (const float*)d_in[8];
  float* out = (float*)d_out;
  char* ws = (char*)d_ws;

  _Float16* whh = (_Float16*)(ws + WHH_OFF);
  _Float16* wih = (_Float16*)(ws + WIH_OFF);
  _Float16* w1  = (_Float16*)(ws + W1_OFF);
  _Float16* w2  = (_Float16*)(ws + W2_OFF);
  float* bias   = (float*)(ws + BIAS_OFF);

  hipLaunchKernelGGL(prep_kernel, dim3(64), dim3(256), 0, stream,
                     W_ih, W_hh, b_ih, b_hh, W1, W2, whh, wih, w1, w2, bias);

  const int B = in_sizes[0] / (TT * NI);  // 262144
  hipLaunchKernelGGL(lstm_mfma, dim3(B / 256), dim3(512), 0, stream,
                     x, whh, wih, w1, w2, bias, b1, b2, out);
}